// Round 5
// baseline (142.430 us; speedup 1.0000x reference)
//
#include <hip/hip_runtime.h>

#define NB 8
#define LL 256
#define DD 256

typedef __attribute__((ext_vector_type(8))) short short8v;  // 8 bf16 (4 VGPR)
typedef __attribute__((ext_vector_type(4))) float f32x4;

__device__ __forceinline__ uint f2bf2(float lo, float hi) {
  uint a = __float_as_uint(lo), b = __float_as_uint(hi);
  uint ra = (a + 0x7FFFu + ((a >> 16) & 1u)) >> 16;
  uint rb = (b + 0x7FFFu + ((b >> 16) & 1u)) & 0xFFFF0000u;
  return ra | rb;
}

// ---------------------------------------------------------------------------
// Kernel 1: A = Q Wa^T, Bm = Q Wb^T, Hj = Q Wd^T (all [B*L, D] fp32 into ws).
// fp32 inputs converted to bf16 inline during LDS staging; 64x64 tile,
// 4 waves (2x2), mfma_f32_16x16x32_bf16. Grid (32, 4, 3).
// ---------------------------------------------------------------------------
__global__ __launch_bounds__(256) void gemm3_mfma(
    const float* __restrict__ Q, const float* __restrict__ Wa,
    const float* __restrict__ Wb, const float* __restrict__ Wd,
    float* __restrict__ A, float* __restrict__ Bm, float* __restrict__ Hj) {
  const int mt = blockIdx.x, nt = blockIdx.y, z = blockIdx.z;
  const float* __restrict__ W = (z == 0) ? Wa : (z == 1) ? Wb : Wd;
  float* __restrict__ Out = (z == 0) ? A : (z == 1) ? Bm : Hj;

  __shared__ __align__(16) ushort Qs[64][32];
  __shared__ __align__(16) ushort Ws[64][32];

  const int tid = threadIdx.x;
  const int m0 = mt * 64, n0 = nt * 64;
  const int srow = tid >> 2, skc = (tid & 3) * 8;
  const int w = tid >> 6, lane = tid & 63;
  const int wm = w >> 1, wn = w & 1;
  const int fr = lane & 15, fk = (lane >> 4) * 8;

  f32x4 acc[2][2] = {};
  for (int k0 = 0; k0 < DD; k0 += 32) {
    {
      const float* src = &Q[(size_t)(m0 + srow) * DD + k0 + skc];
      float4 q0 = *(const float4*)src;
      float4 q1 = *(const float4*)(src + 4);
      uint4 pk = make_uint4(f2bf2(q0.x, q0.y), f2bf2(q0.z, q0.w),
                            f2bf2(q1.x, q1.y), f2bf2(q1.z, q1.w));
      *(uint4*)&Qs[srow][skc] = pk;
      const float* ws_ = &W[(size_t)(n0 + srow) * DD + k0 + skc];
      float4 w0 = *(const float4*)ws_;
      float4 w1 = *(const float4*)(ws_ + 4);
      uint4 pw = make_uint4(f2bf2(w0.x, w0.y), f2bf2(w0.z, w0.w),
                            f2bf2(w1.x, w1.y), f2bf2(w1.z, w1.w));
      *(uint4*)&Ws[srow][skc] = pw;
    }
    __syncthreads();
    short8v a0 = *(const short8v*)&Qs[wm * 32 + fr][fk];
    short8v a1 = *(const short8v*)&Qs[wm * 32 + 16 + fr][fk];
    short8v b0 = *(const short8v*)&Ws[wn * 32 + fr][fk];
    short8v b1 = *(const short8v*)&Ws[wn * 32 + 16 + fr][fk];
    acc[0][0] = __builtin_amdgcn_mfma_f32_16x16x32_bf16(a0, b0, acc[0][0], 0, 0, 0);
    acc[0][1] = __builtin_amdgcn_mfma_f32_16x16x32_bf16(a0, b1, acc[0][1], 0, 0, 0);
    acc[1][0] = __builtin_amdgcn_mfma_f32_16x16x32_bf16(a1, b0, acc[1][0], 0, 0, 0);
    acc[1][1] = __builtin_amdgcn_mfma_f32_16x16x32_bf16(a1, b1, acc[1][1], 0, 0, 0);
    __syncthreads();
  }

  const int rbase = m0 + wm * 32 + (lane >> 4) * 4;
  const int cbase = n0 + wn * 32 + fr;
#pragma unroll
  for (int i = 0; i < 2; ++i)
#pragma unroll
    for (int j = 0; j < 2; ++j)
#pragma unroll
      for (int r = 0; r < 4; ++r)
        Out[(size_t)(rbase + i * 16 + r) * DD + cbase + j * 16] = acc[i][j][r];
}

// ---------------------------------------------------------------------------
// Kernel 2: fused edge-score + masked softmax + aggregation + residual relu
// + tail (sdep -> float). One block per (b, 4-row i-tile):
// grid (64 it, 8 b) = 512 blocks, 256 threads (2 blocks/CU, 2 waves/SIMD).
// Edge: A rows + w2 in registers, B streamed from L2 (4-way lane broadcast),
// c-reduce via shfl_xor over 16 lanes, predicated LDS scatter of t.
// Agg: w[i][j] is wave-uniform per j -> uniform-branch skip of zero weights.
// ---------------------------------------------------------------------------
__global__ __launch_bounds__(256) void fused_kernel(
    const float* __restrict__ Q, const int* __restrict__ sdep,
    const float* __restrict__ w2, const float* __restrict__ A,
    const float* __restrict__ Bm, const float* __restrict__ Hj,
    float* __restrict__ out, float* __restrict__ tail) {
  const int it = blockIdx.x, b = blockIdx.y;
  const int i0 = it * 4;
  const int tid = threadIdx.x;

  __shared__ float Ts[4][260];

  // ---- Phase 0: tail conversion (independent) ----
  {
    int base = (b * 64 + it) * 1024 + tid * 4;
    int4 s = *(const int4*)&sdep[base];
    float4 f;
    f.x = (float)s.x; f.y = (float)s.y; f.z = (float)s.z; f.w = (float)s.w;
    *(float4*)&tail[8 + base] = f;
  }

  // ---- Phase 1: edge scores ----
  const int w = tid >> 6;        // wave -> j-range [w*64, w*64+64)
  const int l = tid & 63;
  const int r = l >> 4;          // i-row 0..3
  const int cg = l & 15;         // c-group of 16
  const int j0 = w * 64;

  float a[16], wv[16];
  {
    const float* Ar = A + ((size_t)(b * LL + i0 + r)) * DD + cg * 16;
#pragma unroll
    for (int ch = 0; ch < 4; ++ch) {
      *(float4*)&a[ch * 4] = *(const float4*)&Ar[ch * 4];
      *(float4*)&wv[ch * 4] = *(const float4*)&w2[cg * 16 + ch * 4];
    }
  }
  const float* Bb = Bm + ((size_t)(b * LL + j0)) * DD + cg * 16;
#pragma unroll 8
  for (int j = 0; j < 64; ++j) {
    float bv[16];
#pragma unroll
    for (int ch = 0; ch < 4; ++ch)
      *(float4*)&bv[ch * 4] = *(const float4*)&Bb[(size_t)j * DD + ch * 4];
    float p = 0.f;
#pragma unroll
    for (int u = 0; u < 16; ++u)
      p = fmaf(wv[u], fmaxf(a[u] + bv[u], 0.f), p);
    p += __shfl_xor(p, 1);
    p += __shfl_xor(p, 2);
    p += __shfl_xor(p, 4);
    p += __shfl_xor(p, 8);
    if ((j & 15) == cg) Ts[r][j0 + j] = p;
  }
  __syncthreads();

  // ---- Phase 2: masked softmax (wave w handles row w) ----
  {
    const int* sr = sdep + ((size_t)(b * LL + i0 + w)) * LL;
    float v[4];
    float m = -3.0e38f;
#pragma unroll
    for (int k = 0; k < 4; ++k) {
      int j = l + 64 * k;
      bool e = sr[j] > 0;
      v[k] = e ? Ts[w][j] : -3.0e38f;
      m = fmaxf(m, v[k]);
    }
#pragma unroll
    for (int off = 32; off >= 1; off >>= 1) m = fmaxf(m, __shfl_xor(m, off));
    float s = 0.f;
#pragma unroll
    for (int k = 0; k < 4; ++k) {
      float e = (v[k] > -1.0e30f) ? __expf(v[k] - m) : 0.f;
      v[k] = e;
      s += e;
    }
#pragma unroll
    for (int off = 32; off >= 1; off >>= 1) s += __shfl_xor(s, off);
    float inv = (s > 0.f) ? 1.0f / s : 0.f;
    __syncthreads();  // all reads of Ts scores done before overwrite
#pragma unroll
    for (int k = 0; k < 4; ++k) Ts[w][l + 64 * k] = v[k] * inv;
  }
  __syncthreads();

  // ---- Phase 3: aggregation with uniform zero-skip + residual relu ----
  {
    const int rr = tid >> 6;   // row (== wave id, uniform)
    const int q = tid & 63;    // c-quad
    const float* Hb = Hj + ((size_t)(b * LL)) * DD + q * 4;
    float acc4[4] = {0.f, 0.f, 0.f, 0.f};
    for (int j4 = 0; j4 < 64; ++j4) {
      float wgt[4];
      *(float4*)wgt = *(const float4*)&Ts[rr][j4 * 4];
#pragma unroll
      for (int u = 0; u < 4; ++u) {
        if (wgt[u] != 0.f) {   // wave-uniform branch: skips VMEM+FMA
          float4 h = *(const float4*)&Hb[(size_t)(j4 * 4 + u) * DD];
          acc4[0] = fmaf(wgt[u], h.x, acc4[0]);
          acc4[1] = fmaf(wgt[u], h.y, acc4[1]);
          acc4[2] = fmaf(wgt[u], h.z, acc4[2]);
          acc4[3] = fmaf(wgt[u], h.w, acc4[3]);
        }
      }
    }
    size_t off = ((size_t)(b * LL + i0 + rr)) * DD + q * 4;
    float4 qv = *(const float4*)&Q[off];
    float4 o;
    o.x = fmaxf(qv.x + acc4[0], 0.f);
    o.y = fmaxf(qv.y + acc4[1], 0.f);
    o.z = fmaxf(qv.z + acc4[2], 0.f);
    o.w = fmaxf(qv.w + acc4[3], 0.f);
    *(float4*)&out[off] = o;
  }
}

// tiny helper for the 8 wordlens (one 1-wave kernel; overlaps with gemm)
__global__ void wordlen_kernel(const int* __restrict__ wl,
                               float* __restrict__ tail) {
  if (threadIdx.x < 8) tail[threadIdx.x] = (float)wl[threadIdx.x];
}

extern "C" void kernel_launch(void* const* d_in, const int* in_sizes, int n_in,
                              void* d_out, int out_size, void* d_ws, size_t ws_size,
                              hipStream_t stream) {
  const float* Q    = (const float*)d_in[0];
  const int*   wl   = (const int*)d_in[1];
  const int*   sdep = (const int*)d_in[2];
  const float* Wa   = (const float*)d_in[3];
  const float* Wb   = (const float*)d_in[4];
  const float* w2   = (const float*)d_in[5];
  const float* Wd   = (const float*)d_in[6];
  float* out = (float*)d_out;
  float* ws  = (float*)d_ws;

  float* A  = ws;              // [2048][256] fp32
  float* Bm = ws + 524288;     // [2048][256] fp32
  float* Hj = ws + 1048576;    // [2048][256] fp32
  float* tail = out + (size_t)NB * LL * DD;

  wordlen_kernel<<<1, 64, 0, stream>>>(wl, tail);
  gemm3_mfma<<<dim3(32, 4, 3), 256, 0, stream>>>(Q, Wa, Wb, Wd, A, Bm, Hj);
  fused_kernel<<<dim3(64, 8), 256, 0, stream>>>(Q, sdep, w2, A, Bm, Hj,
                                                out, tail);
}

// Round 6
// 105.539 us; speedup vs baseline: 1.3496x; 1.3496x over previous
//
#include <hip/hip_runtime.h>

#define NB 8
#define LL 256
#define DD 256

typedef __attribute__((ext_vector_type(8))) short short8v;  // 8 bf16 (4 VGPR)
typedef __attribute__((ext_vector_type(4))) float f32x4;

__device__ __forceinline__ uint f2bf2(float lo, float hi) {
  uint a = __float_as_uint(lo), b = __float_as_uint(hi);
  uint ra = (a + 0x7FFFu + ((a >> 16) & 1u)) >> 16;
  uint rb = (b + 0x7FFFu + ((b >> 16) & 1u)) & 0xFFFF0000u;
  return ra | rb;
}

// ---------------------------------------------------------------------------
// Kernel 1: A = Q Wa^T, Bm = Q Wb^T, Hj = Q Wd^T (all [B*L, D] fp32 into ws).
// fp32 -> bf16 inline during LDS staging; 64x64 tile, 4 waves (2x2),
// mfma_f32_16x16x32_bf16. Grid (32, 4, 3).
// ---------------------------------------------------------------------------
__global__ __launch_bounds__(256) void gemm3_mfma(
    const float* __restrict__ Q, const float* __restrict__ Wa,
    const float* __restrict__ Wb, const float* __restrict__ Wd,
    float* __restrict__ A, float* __restrict__ Bm, float* __restrict__ Hj) {
  const int mt = blockIdx.x, nt = blockIdx.y, z = blockIdx.z;
  const float* __restrict__ W = (z == 0) ? Wa : (z == 1) ? Wb : Wd;
  float* __restrict__ Out = (z == 0) ? A : (z == 1) ? Bm : Hj;

  __shared__ __align__(16) ushort Qs[64][32];
  __shared__ __align__(16) ushort Ws[64][32];

  const int tid = threadIdx.x;
  const int m0 = mt * 64, n0 = nt * 64;
  const int srow = tid >> 2, skc = (tid & 3) * 8;
  const int w = tid >> 6, lane = tid & 63;
  const int wm = w >> 1, wn = w & 1;
  const int fr = lane & 15, fk = (lane >> 4) * 8;

  f32x4 acc[2][2] = {};
  for (int k0 = 0; k0 < DD; k0 += 32) {
    {
      const float* src = &Q[(size_t)(m0 + srow) * DD + k0 + skc];
      float4 q0 = *(const float4*)src;
      float4 q1 = *(const float4*)(src + 4);
      uint4 pk = make_uint4(f2bf2(q0.x, q0.y), f2bf2(q0.z, q0.w),
                            f2bf2(q1.x, q1.y), f2bf2(q1.z, q1.w));
      *(uint4*)&Qs[srow][skc] = pk;
      const float* ws_ = &W[(size_t)(n0 + srow) * DD + k0 + skc];
      float4 w0 = *(const float4*)ws_;
      float4 w1 = *(const float4*)(ws_ + 4);
      uint4 pw = make_uint4(f2bf2(w0.x, w0.y), f2bf2(w0.z, w0.w),
                            f2bf2(w1.x, w1.y), f2bf2(w1.z, w1.w));
      *(uint4*)&Ws[srow][skc] = pw;
    }
    __syncthreads();
    short8v a0 = *(const short8v*)&Qs[wm * 32 + fr][fk];
    short8v a1 = *(const short8v*)&Qs[wm * 32 + 16 + fr][fk];
    short8v b0 = *(const short8v*)&Ws[wn * 32 + fr][fk];
    short8v b1 = *(const short8v*)&Ws[wn * 32 + 16 + fr][fk];
    acc[0][0] = __builtin_amdgcn_mfma_f32_16x16x32_bf16(a0, b0, acc[0][0], 0, 0, 0);
    acc[0][1] = __builtin_amdgcn_mfma_f32_16x16x32_bf16(a0, b1, acc[0][1], 0, 0, 0);
    acc[1][0] = __builtin_amdgcn_mfma_f32_16x16x32_bf16(a1, b0, acc[1][0], 0, 0, 0);
    acc[1][1] = __builtin_amdgcn_mfma_f32_16x16x32_bf16(a1, b1, acc[1][1], 0, 0, 0);
    __syncthreads();
  }

  const int rbase = m0 + wm * 32 + (lane >> 4) * 4;
  const int cbase = n0 + wn * 32 + fr;
#pragma unroll
  for (int i = 0; i < 2; ++i)
#pragma unroll
    for (int j = 0; j < 2; ++j)
#pragma unroll
      for (int r = 0; r < 4; ++r)
        Out[(size_t)(rbase + i * 16 + r) * DD + cbase + j * 16] = acc[i][j][r];
}

// ---------------------------------------------------------------------------
// Kernel 2: fused edge-score + masked softmax + aggregation + residual relu
// + tail (sdep -> float). Grid (64 it, 8 b) = 512 blocks, 256 threads.
// Edge: lane = jp*16+cg; each 16-lane group handles a distinct j per step
//   (4 j in flight -> independent shfl chains), each lane holds all 4 i-rows
//   -> VALU-issue-bound, not latency-bound.
// Agg: unconditional, cooperative j-split across waves (Hj panel read once
//   per block), cross-wave reduction in LDS.
// ---------------------------------------------------------------------------
__global__ __launch_bounds__(256) void fused_kernel(
    const float* __restrict__ Q, const int* __restrict__ sdep,
    const float* __restrict__ w2, const float* __restrict__ A,
    const float* __restrict__ Bm, const float* __restrict__ Hj,
    float* __restrict__ out, float* __restrict__ tail) {
  const int it = blockIdx.x, b = blockIdx.y;
  const int i0 = it * 4;
  const int tid = threadIdx.x;

  __shared__ float Ts[4][260];        // edge scores, then softmax weights
  __shared__ float Red[4][4][256];    // cross-wave agg partials

  // ---- Phase 0: tail conversion (independent VMEM, overlaps edge) ----
  {
    int base = (b * 64 + it) * 1024 + tid * 4;
    int4 s = *(const int4*)&sdep[base];
    float4 f;
    f.x = (float)s.x; f.y = (float)s.y; f.z = (float)s.z; f.w = (float)s.w;
    *(float4*)&tail[8 + base] = f;
  }

  const int w = tid >> 6, l = tid & 63;
  const int j0 = w * 64;

  // ---- Phase 1: edge scores ----
  {
    const int cg = l & 15;   // c-chunk of 16
    const int jp = l >> 4;   // which of 4 parallel j
    float a[4][16], wv[16];
    const float* Ab = A + ((size_t)(b * LL + i0)) * DD + cg * 16;
#pragma unroll
    for (int r = 0; r < 4; ++r)
#pragma unroll
      for (int ch = 0; ch < 4; ++ch)
        *(float4*)&a[r][ch * 4] = *(const float4*)&Ab[(size_t)r * DD + ch * 4];
#pragma unroll
    for (int ch = 0; ch < 4; ++ch)
      *(float4*)&wv[ch * 4] = *(const float4*)&w2[cg * 16 + ch * 4];

    const float* Bb = Bm + ((size_t)(b * LL + j0 + jp)) * DD + cg * 16;
#pragma unroll 2
    for (int step = 0; step < 16; ++step) {
      float bv[16];
#pragma unroll
      for (int ch = 0; ch < 4; ++ch)
        *(float4*)&bv[ch * 4] =
            *(const float4*)&Bb[(size_t)step * 4 * DD + ch * 4];
      float p0 = 0.f, p1 = 0.f, p2 = 0.f, p3 = 0.f;
#pragma unroll
      for (int u = 0; u < 16; ++u) {
        float bb = bv[u], ww = wv[u];
        p0 = fmaf(ww, fmaxf(a[0][u] + bb, 0.f), p0);
        p1 = fmaf(ww, fmaxf(a[1][u] + bb, 0.f), p1);
        p2 = fmaf(ww, fmaxf(a[2][u] + bb, 0.f), p2);
        p3 = fmaf(ww, fmaxf(a[3][u] + bb, 0.f), p3);
      }
      // reduce over the 16 c-lanes of this jp group (4 independent chains)
#pragma unroll
      for (int m = 1; m <= 8; m <<= 1) {
        p0 += __shfl_xor(p0, m);
        p1 += __shfl_xor(p1, m);
        p2 += __shfl_xor(p2, m);
        p3 += __shfl_xor(p3, m);
      }
      int j = j0 + step * 4 + jp;
      float pv = (cg == 0) ? p0 : (cg == 1) ? p1 : (cg == 2) ? p2 : p3;
      if (cg < 4) Ts[cg][j] = pv;   // banks 4*cg+jp+...: conflict-free
    }
  }
  __syncthreads();

  // ---- Phase 2: masked softmax (wave w handles row w) ----
  {
    const int* sr = sdep + ((size_t)(b * LL + i0 + w)) * LL;
    float v[4];
    float m = -3.0e38f;
#pragma unroll
    for (int k = 0; k < 4; ++k) {
      int j = l + 64 * k;
      bool e = sr[j] > 0;
      v[k] = e ? Ts[w][j] : -3.0e38f;
      m = fmaxf(m, v[k]);
    }
#pragma unroll
    for (int off = 32; off >= 1; off >>= 1) m = fmaxf(m, __shfl_xor(m, off));
    float s = 0.f;
#pragma unroll
    for (int k = 0; k < 4; ++k) {
      float e = (v[k] > -1.0e30f) ? __expf(v[k] - m) : 0.f;
      v[k] = e;
      s += e;
    }
#pragma unroll
    for (int off = 32; off >= 1; off >>= 1) s += __shfl_xor(s, off);
    float inv = (s > 0.f) ? 1.0f / s : 0.f;
    __syncthreads();  // all Ts score reads done before overwrite
#pragma unroll
    for (int k = 0; k < 4; ++k) Ts[w][l + 64 * k] = v[k] * inv;
  }
  __syncthreads();

  // ---- Phase 3: aggregation — wave w sums its j-range for ALL 4 rows ----
  {
    const float* Hb = Hj + ((size_t)(b * LL + j0)) * DD + l * 4;
    float acc[4][4] = {};
#pragma unroll 2
    for (int j4 = 0; j4 < 16; ++j4) {
      float tw0[4], tw1[4], tw2[4], tw3[4];
      *(float4*)tw0 = *(const float4*)&Ts[0][j0 + j4 * 4];
      *(float4*)tw1 = *(const float4*)&Ts[1][j0 + j4 * 4];
      *(float4*)tw2 = *(const float4*)&Ts[2][j0 + j4 * 4];
      *(float4*)tw3 = *(const float4*)&Ts[3][j0 + j4 * 4];
#pragma unroll
      for (int u = 0; u < 4; ++u) {
        float4 h = *(const float4*)&Hb[(size_t)(j4 * 4 + u) * DD];
        acc[0][0] = fmaf(tw0[u], h.x, acc[0][0]);
        acc[0][1] = fmaf(tw0[u], h.y, acc[0][1]);
        acc[0][2] = fmaf(tw0[u], h.z, acc[0][2]);
        acc[0][3] = fmaf(tw0[u], h.w, acc[0][3]);
        acc[1][0] = fmaf(tw1[u], h.x, acc[1][0]);
        acc[1][1] = fmaf(tw1[u], h.y, acc[1][1]);
        acc[1][2] = fmaf(tw1[u], h.z, acc[1][2]);
        acc[1][3] = fmaf(tw1[u], h.w, acc[1][3]);
        acc[2][0] = fmaf(tw2[u], h.x, acc[2][0]);
        acc[2][1] = fmaf(tw2[u], h.y, acc[2][1]);
        acc[2][2] = fmaf(tw2[u], h.z, acc[2][2]);
        acc[2][3] = fmaf(tw2[u], h.w, acc[2][3]);
        acc[3][0] = fmaf(tw3[u], h.x, acc[3][0]);
        acc[3][1] = fmaf(tw3[u], h.y, acc[3][1]);
        acc[3][2] = fmaf(tw3[u], h.z, acc[3][2]);
        acc[3][3] = fmaf(tw3[u], h.w, acc[3][3]);
      }
    }
#pragma unroll
    for (int r = 0; r < 4; ++r)
      *(float4*)&Red[w][r][l * 4] = *(float4*)acc[r];
  }
  __syncthreads();

  // ---- Phase 4: cross-wave reduce + residual relu ----
  {
    const int r = tid >> 6, q = tid & 63;
    float4 s0 = *(const float4*)&Red[0][r][q * 4];
    float4 s1 = *(const float4*)&Red[1][r][q * 4];
    float4 s2 = *(const float4*)&Red[2][r][q * 4];
    float4 s3 = *(const float4*)&Red[3][r][q * 4];
    size_t off = ((size_t)(b * LL + i0 + r)) * DD + q * 4;
    float4 qv = *(const float4*)&Q[off];
    float4 o;
    o.x = fmaxf(qv.x + s0.x + s1.x + s2.x + s3.x, 0.f);
    o.y = fmaxf(qv.y + s0.y + s1.y + s2.y + s3.y, 0.f);
    o.z = fmaxf(qv.z + s0.z + s1.z + s2.z + s3.z, 0.f);
    o.w = fmaxf(qv.w + s0.w + s1.w + s2.w + s3.w, 0.f);
    *(float4*)&out[off] = o;
  }
}

// tiny helper for the 8 wordlens (overlaps with gemm)
__global__ void wordlen_kernel(const int* __restrict__ wl,
                               float* __restrict__ tail) {
  if (threadIdx.x < 8) tail[threadIdx.x] = (float)wl[threadIdx.x];
}

extern "C" void kernel_launch(void* const* d_in, const int* in_sizes, int n_in,
                              void* d_out, int out_size, void* d_ws, size_t ws_size,
                              hipStream_t stream) {
  const float* Q    = (const float*)d_in[0];
  const int*   wl   = (const int*)d_in[1];
  const int*   sdep = (const int*)d_in[2];
  const float* Wa   = (const float*)d_in[3];
  const float* Wb   = (const float*)d_in[4];
  const float* w2   = (const float*)d_in[5];
  const float* Wd   = (const float*)d_in[6];
  float* out = (float*)d_out;
  float* ws  = (float*)d_ws;

  float* A  = ws;              // [2048][256] fp32
  float* Bm = ws + 524288;     // [2048][256] fp32
  float* Hj = ws + 1048576;    // [2048][256] fp32
  float* tail = out + (size_t)NB * LL * DD;

  wordlen_kernel<<<1, 64, 0, stream>>>(wl, tail);
  gemm3_mfma<<<dim3(32, 4, 3), 256, 0, stream>>>(Q, Wa, Wb, Wd, A, Bm, Hj);
  fused_kernel<<<dim3(64, 8), 256, 0, stream>>>(Q, sdep, w2, A, Bm, Hj,
                                                out, tail);
}

// Round 7
// 102.918 us; speedup vs baseline: 1.3839x; 1.0255x over previous
//
#include <hip/hip_runtime.h>

#define NB 8
#define LL 256
#define DD 256

typedef __attribute__((ext_vector_type(8))) short short8v;  // 8 bf16 (4 VGPR)
typedef __attribute__((ext_vector_type(4))) float f32x4;

__device__ __forceinline__ uint f2bf2(float lo, float hi) {
  uint a = __float_as_uint(lo), b = __float_as_uint(hi);
  uint ra = (a + 0x7FFFu + ((a >> 16) & 1u)) >> 16;
  uint rb = (b + 0x7FFFu + ((b >> 16) & 1u)) & 0xFFFF0000u;
  return ra | rb;
}

// ---------------------------------------------------------------------------
// Kernel 1: A = Q Wa^T, Bm = Q Wb^T, Hj = Q Wd^T (fp32 into ws) via bf16 MFMA
// (inputs converted inline during LDS staging). 64x64 tile, 4 waves (2x2).
// Grid (32, 4, 3). Also carries the independent tail work: sdep -> float and
// wordlens -> float into d_out (grid-strided, overlaps the GEMM latency).
// ---------------------------------------------------------------------------
__global__ __launch_bounds__(256) void gemm3_mfma(
    const float* __restrict__ Q, const float* __restrict__ Wa,
    const float* __restrict__ Wb, const float* __restrict__ Wd,
    const int* __restrict__ wl, const int* __restrict__ sdep,
    float* __restrict__ A, float* __restrict__ Bm, float* __restrict__ Hj,
    float* __restrict__ tail) {
  const int mt = blockIdx.x, nt = blockIdx.y, z = blockIdx.z;
  const int bid = mt + 32 * (nt + 4 * z);  // 0..383
  const float* __restrict__ W = (z == 0) ? Wa : (z == 1) ? Wb : Wd;
  float* __restrict__ Out = (z == 0) ? A : (z == 1) ? Bm : Hj;

  __shared__ __align__(16) ushort Qs[64][32];
  __shared__ __align__(16) ushort Ws[64][32];

  const int tid = threadIdx.x;
  const int m0 = mt * 64, n0 = nt * 64;
  const int srow = tid >> 2, skc = (tid & 3) * 8;
  const int w = tid >> 6, lane = tid & 63;
  const int wm = w >> 1, wn = w & 1;
  const int fr = lane & 15, fk = (lane >> 4) * 8;

  f32x4 acc[2][2] = {};
  for (int k0 = 0; k0 < DD; k0 += 32) {
    {
      const float* src = &Q[(size_t)(m0 + srow) * DD + k0 + skc];
      float4 q0 = *(const float4*)src;
      float4 q1 = *(const float4*)(src + 4);
      uint4 pk = make_uint4(f2bf2(q0.x, q0.y), f2bf2(q0.z, q0.w),
                            f2bf2(q1.x, q1.y), f2bf2(q1.z, q1.w));
      *(uint4*)&Qs[srow][skc] = pk;
      const float* ws_ = &W[(size_t)(n0 + srow) * DD + k0 + skc];
      float4 w0 = *(const float4*)ws_;
      float4 w1 = *(const float4*)(ws_ + 4);
      uint4 pw = make_uint4(f2bf2(w0.x, w0.y), f2bf2(w0.z, w0.w),
                            f2bf2(w1.x, w1.y), f2bf2(w1.z, w1.w));
      *(uint4*)&Ws[srow][skc] = pw;
    }
    __syncthreads();
    short8v a0 = *(const short8v*)&Qs[wm * 32 + fr][fk];
    short8v a1 = *(const short8v*)&Qs[wm * 32 + 16 + fr][fk];
    short8v b0 = *(const short8v*)&Ws[wn * 32 + fr][fk];
    short8v b1 = *(const short8v*)&Ws[wn * 32 + 16 + fr][fk];
    acc[0][0] = __builtin_amdgcn_mfma_f32_16x16x32_bf16(a0, b0, acc[0][0], 0, 0, 0);
    acc[0][1] = __builtin_amdgcn_mfma_f32_16x16x32_bf16(a0, b1, acc[0][1], 0, 0, 0);
    acc[1][0] = __builtin_amdgcn_mfma_f32_16x16x32_bf16(a1, b0, acc[1][0], 0, 0, 0);
    acc[1][1] = __builtin_amdgcn_mfma_f32_16x16x32_bf16(a1, b1, acc[1][1], 0, 0, 0);
    __syncthreads();
  }

  const int rbase = m0 + wm * 32 + (lane >> 4) * 4;
  const int cbase = n0 + wn * 32 + fr;
#pragma unroll
  for (int i = 0; i < 2; ++i)
#pragma unroll
    for (int j = 0; j < 2; ++j)
#pragma unroll
      for (int r = 0; r < 4; ++r)
        Out[(size_t)(rbase + i * 16 + r) * DD + cbase + j * 16] = acc[i][j][r];

  // ---- tail: sdep (131072 int4) + 8 wordlens -> float, grid-strided ----
  for (int t = bid * 256 + tid; t < 131072; t += 384 * 256) {
    int4 s = *(const int4*)&sdep[(size_t)t * 4];
    float4 f;
    f.x = (float)s.x; f.y = (float)s.y; f.z = (float)s.z; f.w = (float)s.w;
    *(float4*)&tail[8 + (size_t)t * 4] = f;
  }
  if (bid == 0 && tid < 8) tail[tid] = (float)wl[tid];
}

// ---------------------------------------------------------------------------
// Kernel 2: fused edge-score + masked softmax + aggregation + residual relu.
// Flat grid 256 blocks (b = bid&7 -> same-b blocks share an XCD's L2),
// 512 threads (8 waves), 8-row i-tiles.
// Edge: 8 A-rows in registers per lane (amortizes B reads), wave w owns
//   j-panel [32w,32w+32), 4 j in flight, 8 independent shfl chains.
// Agg: two 4-row passes, wave-cooperative j-split, LDS cross-wave reduce.
// ---------------------------------------------------------------------------
__global__ __launch_bounds__(512, 2) void fused_kernel(
    const float* __restrict__ Q, const int* __restrict__ sdep,
    const float* __restrict__ w2, const float* __restrict__ A,
    const float* __restrict__ Bm, const float* __restrict__ Hj,
    float* __restrict__ out) {
  const int bid = blockIdx.x;
  const int b = bid & 7, it = bid >> 3;
  const int i0 = it * 8;
  const int tid = threadIdx.x;
  const int w = tid >> 6, l = tid & 63;
  const int j0 = w * 32;

  __shared__ float Ts[8][260];        // edge scores -> softmax weights
  __shared__ float Red[8][4][256];    // cross-wave agg partials (32 KB)

  // ---- Phase 1: edge scores ----
  {
    const int jp = l >> 4;   // 4 parallel j per wave
    const int cg = l & 15;   // c-chunk of 16
    float a[8][16], wv[16];
    const float* Ab = A + ((size_t)(b * LL + i0)) * DD + cg * 16;
#pragma unroll
    for (int r = 0; r < 8; ++r)
#pragma unroll
      for (int ch = 0; ch < 4; ++ch)
        *(float4*)&a[r][ch * 4] = *(const float4*)&Ab[(size_t)r * DD + ch * 4];
#pragma unroll
    for (int ch = 0; ch < 4; ++ch)
      *(float4*)&wv[ch * 4] = *(const float4*)&w2[cg * 16 + ch * 4];

    const float* Bb = Bm + ((size_t)(b * LL + j0 + jp)) * DD + cg * 16;
#pragma unroll 2
    for (int s = 0; s < 8; ++s) {
      float bv[16];
#pragma unroll
      for (int ch = 0; ch < 4; ++ch)
        *(float4*)&bv[ch * 4] =
            *(const float4*)&Bb[(size_t)(s * 4) * DD + ch * 4];
      float p0 = 0.f, p1 = 0.f, p2 = 0.f, p3 = 0.f;
      float p4 = 0.f, p5 = 0.f, p6 = 0.f, p7 = 0.f;
#pragma unroll
      for (int u = 0; u < 16; ++u) {
        float bb = bv[u], ww = wv[u];
        p0 = fmaf(ww, fmaxf(a[0][u] + bb, 0.f), p0);
        p1 = fmaf(ww, fmaxf(a[1][u] + bb, 0.f), p1);
        p2 = fmaf(ww, fmaxf(a[2][u] + bb, 0.f), p2);
        p3 = fmaf(ww, fmaxf(a[3][u] + bb, 0.f), p3);
        p4 = fmaf(ww, fmaxf(a[4][u] + bb, 0.f), p4);
        p5 = fmaf(ww, fmaxf(a[5][u] + bb, 0.f), p5);
        p6 = fmaf(ww, fmaxf(a[6][u] + bb, 0.f), p6);
        p7 = fmaf(ww, fmaxf(a[7][u] + bb, 0.f), p7);
      }
#pragma unroll
      for (int m = 1; m <= 8; m <<= 1) {
        p0 += __shfl_xor(p0, m); p1 += __shfl_xor(p1, m);
        p2 += __shfl_xor(p2, m); p3 += __shfl_xor(p3, m);
        p4 += __shfl_xor(p4, m); p5 += __shfl_xor(p5, m);
        p6 += __shfl_xor(p6, m); p7 += __shfl_xor(p7, m);
      }
      // lane cg (<8) writes row cg; static select chain (no scratch)
      float pv = p0;
      pv = (cg == 1) ? p1 : pv; pv = (cg == 2) ? p2 : pv;
      pv = (cg == 3) ? p3 : pv; pv = (cg == 4) ? p4 : pv;
      pv = (cg == 5) ? p5 : pv; pv = (cg == 6) ? p6 : pv;
      pv = (cg == 7) ? p7 : pv;
      if (cg < 8) Ts[cg][j0 + s * 4 + jp] = pv;  // banks cg*4+jp: conflict-free
    }
  }
  __syncthreads();

  // ---- Phase 2: masked softmax (wave w -> row w) ----
  {
    const int* sr = sdep + ((size_t)(b * LL + i0 + w)) * LL;
    float v[4];
    float m = -3.0e38f;
#pragma unroll
    for (int k = 0; k < 4; ++k) {
      int j = l + 64 * k;
      bool e = sr[j] > 0;
      v[k] = e ? Ts[w][j] : -3.0e38f;
      m = fmaxf(m, v[k]);
    }
#pragma unroll
    for (int off = 32; off >= 1; off >>= 1) m = fmaxf(m, __shfl_xor(m, off));
    float s = 0.f;
#pragma unroll
    for (int k = 0; k < 4; ++k) {
      float e = (v[k] > -1.0e30f) ? __expf(v[k] - m) : 0.f;
      v[k] = e;
      s += e;
    }
#pragma unroll
    for (int off = 32; off >= 1; off >>= 1) s += __shfl_xor(s, off);
    float inv = (s > 0.f) ? 1.0f / s : 0.f;
    __syncthreads();  // all Ts score reads done before overwrite
#pragma unroll
    for (int k = 0; k < 4; ++k) Ts[w][l + 64 * k] = v[k] * inv;
  }
  __syncthreads();

  // ---- Phases 3+4: aggregation in two 4-row passes + residual relu ----
  const float* Hb = Hj + ((size_t)(b * LL + j0)) * DD + l * 4;
#pragma unroll
  for (int g = 0; g < 2; ++g) {
    {
      float acc[4][4] = {};
#pragma unroll 2
      for (int j4 = 0; j4 < 8; ++j4) {
        float tw0[4], tw1[4], tw2[4], tw3[4];
        *(float4*)tw0 = *(const float4*)&Ts[g * 4 + 0][j0 + j4 * 4];
        *(float4*)tw1 = *(const float4*)&Ts[g * 4 + 1][j0 + j4 * 4];
        *(float4*)tw2 = *(const float4*)&Ts[g * 4 + 2][j0 + j4 * 4];
        *(float4*)tw3 = *(const float4*)&Ts[g * 4 + 3][j0 + j4 * 4];
#pragma unroll
        for (int u = 0; u < 4; ++u) {
          float4 h = *(const float4*)&Hb[(size_t)(j4 * 4 + u) * DD];
          acc[0][0] = fmaf(tw0[u], h.x, acc[0][0]);
          acc[0][1] = fmaf(tw0[u], h.y, acc[0][1]);
          acc[0][2] = fmaf(tw0[u], h.z, acc[0][2]);
          acc[0][3] = fmaf(tw0[u], h.w, acc[0][3]);
          acc[1][0] = fmaf(tw1[u], h.x, acc[1][0]);
          acc[1][1] = fmaf(tw1[u], h.y, acc[1][1]);
          acc[1][2] = fmaf(tw1[u], h.z, acc[1][2]);
          acc[1][3] = fmaf(tw1[u], h.w, acc[1][3]);
          acc[2][0] = fmaf(tw2[u], h.x, acc[2][0]);
          acc[2][1] = fmaf(tw2[u], h.y, acc[2][1]);
          acc[2][2] = fmaf(tw2[u], h.z, acc[2][2]);
          acc[2][3] = fmaf(tw2[u], h.w, acc[2][3]);
          acc[3][0] = fmaf(tw3[u], h.x, acc[3][0]);
          acc[3][1] = fmaf(tw3[u], h.y, acc[3][1]);
          acc[3][2] = fmaf(tw3[u], h.z, acc[3][2]);
          acc[3][3] = fmaf(tw3[u], h.w, acc[3][3]);
        }
      }
#pragma unroll
      for (int r = 0; r < 4; ++r)
        *(float4*)&Red[w][r][l * 4] = *(float4*)acc[r];
    }
    __syncthreads();
    if (tid < 256) {
      const int r = tid >> 6, q = tid & 63;
      float4 s0 = *(const float4*)&Red[0][r][q * 4];
      float4 s1 = *(const float4*)&Red[1][r][q * 4];
      float4 s2 = *(const float4*)&Red[2][r][q * 4];
      float4 s3 = *(const float4*)&Red[3][r][q * 4];
      float4 s4 = *(const float4*)&Red[4][r][q * 4];
      float4 s5 = *(const float4*)&Red[5][r][q * 4];
      float4 s6 = *(const float4*)&Red[6][r][q * 4];
      float4 s7 = *(const float4*)&Red[7][r][q * 4];
      size_t off = ((size_t)(b * LL + i0 + g * 4 + r)) * DD + q * 4;
      float4 qv = *(const float4*)&Q[off];
      float4 o;
      o.x = fmaxf(qv.x + ((s0.x + s1.x) + (s2.x + s3.x)) +
                          ((s4.x + s5.x) + (s6.x + s7.x)), 0.f);
      o.y = fmaxf(qv.y + ((s0.y + s1.y) + (s2.y + s3.y)) +
                          ((s4.y + s5.y) + (s6.y + s7.y)), 0.f);
      o.z = fmaxf(qv.z + ((s0.z + s1.z) + (s2.z + s3.z)) +
                          ((s4.z + s5.z) + (s6.z + s7.z)), 0.f);
      o.w = fmaxf(qv.w + ((s0.w + s1.w) + (s2.w + s3.w)) +
                          ((s4.w + s5.w) + (s6.w + s7.w)), 0.f);
      *(float4*)&out[off] = o;
    }
    __syncthreads();  // Red reuse in pass 2
  }
}

extern "C" void kernel_launch(void* const* d_in, const int* in_sizes, int n_in,
                              void* d_out, int out_size, void* d_ws, size_t ws_size,
                              hipStream_t stream) {
  const float* Q    = (const float*)d_in[0];
  const int*   wl   = (const int*)d_in[1];
  const int*   sdep = (const int*)d_in[2];
  const float* Wa   = (const float*)d_in[3];
  const float* Wb   = (const float*)d_in[4];
  const float* w2   = (const float*)d_in[5];
  const float* Wd   = (const float*)d_in[6];
  float* out = (float*)d_out;
  float* ws  = (float*)d_ws;

  float* A  = ws;              // [2048][256] fp32
  float* Bm = ws + 524288;     // [2048][256] fp32
  float* Hj = ws + 1048576;    // [2048][256] fp32
  float* tail = out + (size_t)NB * LL * DD;

  gemm3_mfma<<<dim3(32, 4, 3), 256, 0, stream>>>(Q, Wa, Wb, Wd, wl, sdep,
                                                 A, Bm, Hj, tail);
  fused_kernel<<<256, 512, 0, stream>>>(Q, sdep, w2, A, Bm, Hj, out);
}

// Round 8
// 100.665 us; speedup vs baseline: 1.4149x; 1.0224x over previous
//
#include <hip/hip_runtime.h>

#define NB 8
#define LL 256
#define DD 256

typedef __attribute__((ext_vector_type(8))) short short8v;  // 8 bf16 (4 VGPR)
typedef __attribute__((ext_vector_type(4))) float f32x4;
typedef __attribute__((ext_vector_type(2))) float f32x2;

#if defined(__has_builtin)
#if __has_builtin(__builtin_elementwise_fma) && __has_builtin(__builtin_elementwise_max)
#define USE_PK 1
#endif
#endif

__device__ __forceinline__ uint f2bf2(float lo, float hi) {
  uint a = __float_as_uint(lo), b = __float_as_uint(hi);
  uint ra = (a + 0x7FFFu + ((a >> 16) & 1u)) >> 16;
  uint rb = (b + 0x7FFFu + ((b >> 16) & 1u)) & 0xFFFF0000u;
  return ra | rb;
}

// ---------------------------------------------------------------------------
// Kernel 1: A = Q Wa^T, Bm = Q Wb^T, Hj = Q Wd^T (fp32 into ws) via bf16 MFMA
// (inputs converted inline during LDS staging). 64x32 tiles, 4 waves (2x2),
// grid (32, 8, 3) = 768 blocks -> 3 blocks/CU, 3 waves/SIMD (latency hiding).
// Also carries tail work: sdep -> float, wordlens -> float into d_out.
// ---------------------------------------------------------------------------
__global__ __launch_bounds__(256, 3) void gemm3_mfma(
    const float* __restrict__ Q, const float* __restrict__ Wa,
    const float* __restrict__ Wb, const float* __restrict__ Wd,
    const int* __restrict__ wl, const int* __restrict__ sdep,
    float* __restrict__ A, float* __restrict__ Bm, float* __restrict__ Hj,
    float* __restrict__ tail) {
  const int mt = blockIdx.x, nt = blockIdx.y, z = blockIdx.z;
  const int bid = mt + 32 * (nt + 8 * z);  // 0..767
  const float* __restrict__ W = (z == 0) ? Wa : (z == 1) ? Wb : Wd;
  float* __restrict__ Out = (z == 0) ? A : (z == 1) ? Bm : Hj;

  __shared__ __align__(16) ushort Qs[64][32];
  __shared__ __align__(16) ushort Ws[32][32];

  const int tid = threadIdx.x;
  const int m0 = mt * 64, n0 = nt * 32;
  const int srow = tid >> 2, skc = (tid & 3) * 8;
  const int w = tid >> 6, lane = tid & 63;
  const int wm = w >> 1, wn = w & 1;
  const int fr = lane & 15, fk = (lane >> 4) * 8;

  f32x4 acc[2] = {};
  for (int k0 = 0; k0 < DD; k0 += 32) {
    {
      const float* src = &Q[(size_t)(m0 + srow) * DD + k0 + skc];
      float4 q0 = *(const float4*)src;
      float4 q1 = *(const float4*)(src + 4);
      uint4 pk = make_uint4(f2bf2(q0.x, q0.y), f2bf2(q0.z, q0.w),
                            f2bf2(q1.x, q1.y), f2bf2(q1.z, q1.w));
      *(uint4*)&Qs[srow][skc] = pk;
    }
    if (tid < 128) {
      const float* ws_ = &W[(size_t)(n0 + srow) * DD + k0 + skc];
      float4 w0 = *(const float4*)ws_;
      float4 w1 = *(const float4*)(ws_ + 4);
      uint4 pw = make_uint4(f2bf2(w0.x, w0.y), f2bf2(w0.z, w0.w),
                            f2bf2(w1.x, w1.y), f2bf2(w1.z, w1.w));
      *(uint4*)&Ws[srow][skc] = pw;
    }
    __syncthreads();
    short8v a0 = *(const short8v*)&Qs[wm * 32 + fr][fk];
    short8v a1 = *(const short8v*)&Qs[wm * 32 + 16 + fr][fk];
    short8v b0 = *(const short8v*)&Ws[wn * 16 + fr][fk];
    acc[0] = __builtin_amdgcn_mfma_f32_16x16x32_bf16(a0, b0, acc[0], 0, 0, 0);
    acc[1] = __builtin_amdgcn_mfma_f32_16x16x32_bf16(a1, b0, acc[1], 0, 0, 0);
    __syncthreads();
  }

  const int rbase = m0 + wm * 32 + (lane >> 4) * 4;
  const int cbase = n0 + wn * 16 + fr;
#pragma unroll
  for (int i = 0; i < 2; ++i)
#pragma unroll
    for (int r = 0; r < 4; ++r)
      Out[(size_t)(rbase + i * 16 + r) * DD + cbase] = acc[i][r];

  // ---- tail: sdep (131072 int4) + 8 wordlens -> float ----
  {
    int t = bid * 256 + tid;
    if (t < 131072) {
      int4 s = *(const int4*)&sdep[(size_t)t * 4];
      float4 f;
      f.x = (float)s.x; f.y = (float)s.y; f.z = (float)s.z; f.w = (float)s.w;
      *(float4*)&tail[8 + (size_t)t * 4] = f;
    }
  }
  if (bid == 0 && tid < 8) tail[tid] = (float)wl[tid];
}

// ---------------------------------------------------------------------------
// Kernel 2: fused edge-score + masked softmax + aggregation + residual relu.
// Flat grid 256 blocks (b = bid&7), 512 threads (8 waves), 8-row i-tiles.
// Edge: 8 A-rows in registers per lane, packed-f32 (v_pk_*) inner loop,
//   wave w owns j-panel [32w,32w+32), 4 j in flight, 8 shfl chains.
// Agg: two 4-row passes, wave-cooperative j-split, LDS cross-wave reduce.
// ---------------------------------------------------------------------------
__global__ __launch_bounds__(512, 2) void fused_kernel(
    const float* __restrict__ Q, const int* __restrict__ sdep,
    const float* __restrict__ w2, const float* __restrict__ A,
    const float* __restrict__ Bm, const float* __restrict__ Hj,
    float* __restrict__ out) {
  const int bid = blockIdx.x;
  const int b = bid & 7, it = bid >> 3;
  const int i0 = it * 8;
  const int tid = threadIdx.x;
  const int w = tid >> 6, l = tid & 63;
  const int j0 = w * 32;

  __shared__ float Ts[8][260];        // edge scores -> softmax weights
  __shared__ float Red[8][4][256];    // cross-wave agg partials (32 KB)

  // ---- Phase 1: edge scores ----
  {
    const int jp = l >> 4;   // 4 parallel j per wave
    const int cg = l & 15;   // c-chunk of 16
    f32x2 a2[8][8], wv2[8];
    const float* Ab = A + ((size_t)(b * LL + i0)) * DD + cg * 16;
#pragma unroll
    for (int r = 0; r < 8; ++r)
#pragma unroll
      for (int ch = 0; ch < 4; ++ch) {
        float4 t = *(const float4*)&Ab[(size_t)r * DD + ch * 4];
        a2[r][ch * 2] = (f32x2){t.x, t.y};
        a2[r][ch * 2 + 1] = (f32x2){t.z, t.w};
      }
#pragma unroll
    for (int ch = 0; ch < 4; ++ch) {
      float4 t = *(const float4*)&w2[cg * 16 + ch * 4];
      wv2[ch * 2] = (f32x2){t.x, t.y};
      wv2[ch * 2 + 1] = (f32x2){t.z, t.w};
    }

    const float* Bb = Bm + ((size_t)(b * LL + j0 + jp)) * DD + cg * 16;
#pragma unroll 2
    for (int s = 0; s < 8; ++s) {
      f32x2 bv2[8];
#pragma unroll
      for (int ch = 0; ch < 4; ++ch) {
        float4 t = *(const float4*)&Bb[(size_t)(s * 4) * DD + ch * 4];
        bv2[ch * 2] = (f32x2){t.x, t.y};
        bv2[ch * 2 + 1] = (f32x2){t.z, t.w};
      }
      f32x2 p2[8] = {};
#pragma unroll
      for (int u = 0; u < 8; ++u) {
        f32x2 bb = bv2[u], ww = wv2[u];
#pragma unroll
        for (int r = 0; r < 8; ++r) {
#ifdef USE_PK
          f32x2 sm = __builtin_elementwise_max(a2[r][u] + bb, (f32x2){0.f, 0.f});
          p2[r] = __builtin_elementwise_fma(ww, sm, p2[r]);
#else
          f32x2 t0 = a2[r][u] + bb;
          f32x2 sm = {fmaxf(t0.x, 0.f), fmaxf(t0.y, 0.f)};
          p2[r].x = fmaf(ww.x, sm.x, p2[r].x);
          p2[r].y = fmaf(ww.y, sm.y, p2[r].y);
#endif
        }
      }
      float p0 = p2[0].x + p2[0].y, p1 = p2[1].x + p2[1].y;
      float p2s = p2[2].x + p2[2].y, p3 = p2[3].x + p2[3].y;
      float p4 = p2[4].x + p2[4].y, p5 = p2[5].x + p2[5].y;
      float p6 = p2[6].x + p2[6].y, p7 = p2[7].x + p2[7].y;
#pragma unroll
      for (int m = 1; m <= 8; m <<= 1) {
        p0 += __shfl_xor(p0, m); p1 += __shfl_xor(p1, m);
        p2s += __shfl_xor(p2s, m); p3 += __shfl_xor(p3, m);
        p4 += __shfl_xor(p4, m); p5 += __shfl_xor(p5, m);
        p6 += __shfl_xor(p6, m); p7 += __shfl_xor(p7, m);
      }
      float pv = p0;
      pv = (cg == 1) ? p1 : pv; pv = (cg == 2) ? p2s : pv;
      pv = (cg == 3) ? p3 : pv; pv = (cg == 4) ? p4 : pv;
      pv = (cg == 5) ? p5 : pv; pv = (cg == 6) ? p6 : pv;
      pv = (cg == 7) ? p7 : pv;
      if (cg < 8) Ts[cg][j0 + s * 4 + jp] = pv;  // banks 4cg+jp: conflict-free
    }
  }
  __syncthreads();

  // ---- Phase 2: masked softmax (wave w -> row w) ----
  {
    const int* sr = sdep + ((size_t)(b * LL + i0 + w)) * LL;
    float v[4];
    float m = -3.0e38f;
#pragma unroll
    for (int k = 0; k < 4; ++k) {
      int j = l + 64 * k;
      bool e = sr[j] > 0;
      v[k] = e ? Ts[w][j] : -3.0e38f;
      m = fmaxf(m, v[k]);
    }
#pragma unroll
    for (int off = 32; off >= 1; off >>= 1) m = fmaxf(m, __shfl_xor(m, off));
    float s = 0.f;
#pragma unroll
    for (int k = 0; k < 4; ++k) {
      float e = (v[k] > -1.0e30f) ? __expf(v[k] - m) : 0.f;
      v[k] = e;
      s += e;
    }
#pragma unroll
    for (int off = 32; off >= 1; off >>= 1) s += __shfl_xor(s, off);
    float inv = (s > 0.f) ? 1.0f / s : 0.f;
    __syncthreads();  // all Ts score reads done before overwrite
#pragma unroll
    for (int k = 0; k < 4; ++k) Ts[w][l + 64 * k] = v[k] * inv;
  }
  __syncthreads();

  // ---- Phases 3+4: aggregation in two 4-row passes + residual relu ----
  const float* Hb = Hj + ((size_t)(b * LL + j0)) * DD + l * 4;
#pragma unroll
  for (int g = 0; g < 2; ++g) {
    {
      float acc[4][4] = {};
#pragma unroll 2
      for (int j4 = 0; j4 < 8; ++j4) {
        float tw0[4], tw1[4], tw2[4], tw3[4];
        *(float4*)tw0 = *(const float4*)&Ts[g * 4 + 0][j0 + j4 * 4];
        *(float4*)tw1 = *(const float4*)&Ts[g * 4 + 1][j0 + j4 * 4];
        *(float4*)tw2 = *(const float4*)&Ts[g * 4 + 2][j0 + j4 * 4];
        *(float4*)tw3 = *(const float4*)&Ts[g * 4 + 3][j0 + j4 * 4];
#pragma unroll
        for (int u = 0; u < 4; ++u) {
          float4 h = *(const float4*)&Hb[(size_t)(j4 * 4 + u) * DD];
          acc[0][0] = fmaf(tw0[u], h.x, acc[0][0]);
          acc[0][1] = fmaf(tw0[u], h.y, acc[0][1]);
          acc[0][2] = fmaf(tw0[u], h.z, acc[0][2]);
          acc[0][3] = fmaf(tw0[u], h.w, acc[0][3]);
          acc[1][0] = fmaf(tw1[u], h.x, acc[1][0]);
          acc[1][1] = fmaf(tw1[u], h.y, acc[1][1]);
          acc[1][2] = fmaf(tw1[u], h.z, acc[1][2]);
          acc[1][3] = fmaf(tw1[u], h.w, acc[1][3]);
          acc[2][0] = fmaf(tw2[u], h.x, acc[2][0]);
          acc[2][1] = fmaf(tw2[u], h.y, acc[2][1]);
          acc[2][2] = fmaf(tw2[u], h.z, acc[2][2]);
          acc[2][3] = fmaf(tw2[u], h.w, acc[2][3]);
          acc[3][0] = fmaf(tw3[u], h.x, acc[3][0]);
          acc[3][1] = fmaf(tw3[u], h.y, acc[3][1]);
          acc[3][2] = fmaf(tw3[u], h.z, acc[3][2]);
          acc[3][3] = fmaf(tw3[u], h.w, acc[3][3]);
        }
      }
#pragma unroll
      for (int r = 0; r < 4; ++r)
        *(float4*)&Red[w][r][l * 4] = *(float4*)acc[r];
    }
    __syncthreads();
    if (tid < 256) {
      const int r = tid >> 6, q = tid & 63;
      float4 s0 = *(const float4*)&Red[0][r][q * 4];
      float4 s1 = *(const float4*)&Red[1][r][q * 4];
      float4 s2 = *(const float4*)&Red[2][r][q * 4];
      float4 s3 = *(const float4*)&Red[3][r][q * 4];
      float4 s4 = *(const float4*)&Red[4][r][q * 4];
      float4 s5 = *(const float4*)&Red[5][r][q * 4];
      float4 s6 = *(const float4*)&Red[6][r][q * 4];
      float4 s7 = *(const float4*)&Red[7][r][q * 4];
      size_t off = ((size_t)(b * LL + i0 + g * 4 + r)) * DD + q * 4;
      float4 qv = *(const float4*)&Q[off];
      float4 o;
      o.x = fmaxf(qv.x + ((s0.x + s1.x) + (s2.x + s3.x)) +
                          ((s4.x + s5.x) + (s6.x + s7.x)), 0.f);
      o.y = fmaxf(qv.y + ((s0.y + s1.y) + (s2.y + s3.y)) +
                          ((s4.y + s5.y) + (s6.y + s7.y)), 0.f);
      o.z = fmaxf(qv.z + ((s0.z + s1.z) + (s2.z + s3.z)) +
                          ((s4.z + s5.z) + (s6.z + s7.z)), 0.f);
      o.w = fmaxf(qv.w + ((s0.w + s1.w) + (s2.w + s3.w)) +
                          ((s4.w + s5.w) + (s6.w + s7.w)), 0.f);
      *(float4*)&out[off] = o;
    }
    __syncthreads();  // Red reuse in pass 2
  }
}

extern "C" void kernel_launch(void* const* d_in, const int* in_sizes, int n_in,
                              void* d_out, int out_size, void* d_ws, size_t ws_size,
                              hipStream_t stream) {
  const float* Q    = (const float*)d_in[0];
  const int*   wl   = (const int*)d_in[1];
  const int*   sdep = (const int*)d_in[2];
  const float* Wa   = (const float*)d_in[3];
  const float* Wb   = (const float*)d_in[4];
  const float* w2   = (const float*)d_in[5];
  const float* Wd   = (const float*)d_in[6];
  float* out = (float*)d_out;
  float* ws  = (float*)d_ws;

  float* A  = ws;              // [2048][256] fp32
  float* Bm = ws + 524288;     // [2048][256] fp32
  float* Hj = ws + 1048576;    // [2048][256] fp32
  float* tail = out + (size_t)NB * LL * DD;

  gemm3_mfma<<<dim3(32, 8, 3), 256, 0, stream>>>(Q, Wa, Wb, Wd, wl, sdep,
                                                 A, Bm, Hj, tail);
  fused_kernel<<<256, 512, 0, stream>>>(Q, sdep, w2, A, Bm, Hj, out);
}